// Round 2
// baseline (78.362 us; speedup 1.0000x reference)
//
#include <hip/hip_runtime.h>

// ReduceBoundingBoxes NMS — 2-launch version.
//   flat[i,c] = X[c*n+i], n = 6400
//   valid = f0 > 0.9 ; b5 = (f0, f1, f0+f2, f1+f3, f4)
//   stable sort valid desc by score; greedy NMS on b5[:,1:5]
//
// Identities (exact in fp):
//  1) rank(i) among valid == #{j valid: sj>si || (sj==si && j<i)}; computable
//     over the COMPACTED valid set since sj>=si>0.9 implies j valid.
//  2) clamped-area==0 boxes have IoU exactly 0 with everything, so greedy
//     NMS == greedy NMS over the positive-area subset only (M ~ 1).
//
// Perf model from rounds 0/1: timed path ~= 40us poison-fill floor + our
// work. Round-1 single block spent ~30us on one CU (zeroing drain, serialized
// LDS atomics, 2560 scattered cold gathers, 19K-cycle LDS rank sweep).
// K1 spreads zeroing/compaction/gathers over 32 CUs and emits complete
// records; K2's single block only ranks V~640 scores in LDS (2 entries per
// thread per ds_read_b128) and runs the tiny NMS.

#define K1B   32     // K1 grid
#define K1T   256    // K1 block
#define CAP   256    // records per block region (slice is 200 scores max)
#define MAXV  2048   // total valid capacity (V ~ 640 expected)
#define MAXM  256    // positive-area list capacity (M ~ 1 expected)
#define NTH   1024   // K2 block

// ---- K1: zero out; per-block compact valid -> full records in ws ----
__global__ __launch_bounds__(K1T) void k_compact(
    const float* __restrict__ X, float* __restrict__ out,
    float* __restrict__ recs, int* __restrict__ counts, int n, int out_n) {
  __shared__ int lcnt;
  const int b = blockIdx.x, t = threadIdx.x;
  if (t == 0) lcnt = 0;
  __syncthreads();

  // zero output (distributed)
  const int gid = b * K1T + t;
  float4* out4 = (float4*)out;
  const int o4 = out_n >> 2;
  for (int i = gid; i < o4; i += K1B * K1T)
    out4[i] = make_float4(0.f, 0.f, 0.f, 0.f);
  for (int i = (o4 << 2) + gid; i < out_n; i += K1B * K1T) out[i] = 0.f;

  // this block's score slice (float4 granularity)
  const int n4 = n >> 2;
  const int sl = (n4 + K1B - 1) / K1B;
  const int q0 = b * sl, q1 = min(q0 + sl, n4);
  const float4* X4 = (const float4*)X;
  float* myrec = recs + (size_t)b * CAP * 8;
  for (int q = q0 + t; q < q1; q += K1T) {
    float4 v = X4[q];
    float vv[4] = {v.x, v.y, v.z, v.w};
    #pragma unroll
    for (int k = 0; k < 4; ++k) {
      float s = vv[k];
      if (s > 0.9f) {
        int idx = 4 * q + k;
        int p = atomicAdd(&lcnt, 1);
        if (p < CAP) {
          float f1 = X[n + idx], f2 = X[2 * n + idx];
          float f3 = X[3 * n + idx], f4v = X[4 * n + idx];
          float c2 = s + f2, c3 = f1 + f3;             // reference-exact fp
          float w = fmaxf(c3 - f1, 0.f);
          float h = fmaxf(f4v - c2, 0.f);
          float area = w * h;
          float4* e = (float4*)(myrec + (size_t)p * 8);
          e[0] = make_float4(s, f1, c2, c3);
          e[1] = make_float4(f4v, area, __int_as_float(idx), 0.f);
        }
      }
    }
  }
  // scalar tail (none for n=6400): block 0 handles it
  if (b == 0) {
    for (int i = (n4 << 2) + t; i < n; i += K1T) {
      float s = X[i];
      if (s > 0.9f) {
        int p = atomicAdd(&lcnt, 1);
        if (p < CAP) {
          float f1 = X[n + i], f2 = X[2 * n + i];
          float f3 = X[3 * n + i], f4v = X[4 * n + i];
          float c2 = s + f2, c3 = f1 + f3;
          float w = fmaxf(c3 - f1, 0.f);
          float h = fmaxf(f4v - c2, 0.f);
          float area = w * h;
          float4* e = (float4*)(myrec + (size_t)p * 8);
          e[0] = make_float4(s, f1, c2, c3);
          e[1] = make_float4(f4v, area, __int_as_float(i), 0.f);
        }
      }
    }
  }
  __syncthreads();
  if (t == 0) counts[b] = min(lcnt, CAP);
}

// ---- K2: prefix counts, stage records to LDS, rank, write rows, NMS ----
__global__ __launch_bounds__(NTH, 1) void k_rank_nms(
    const float* __restrict__ recs, const int* __restrict__ counts,
    float* __restrict__ out) {
  __shared__ int scnt[K1B];
  __shared__ int soff[K1B + 1];
  __shared__ __align__(16) float srec[MAXV][8];        // 64 KB
  __shared__ __align__(16) float cscore[MAXV];         // padded sweep array
  __shared__ unsigned cidx[MAXV];
  __shared__ int s_m, sflag;
  __shared__ int   prank[MAXM];
  __shared__ float pbox[MAXM][4];
  __shared__ float parea[MAXM];
  __shared__ int   srnk[MAXM];
  __shared__ float sbox[MAXM][4];
  __shared__ float sarea[MAXM];
  __shared__ int   skeep[MAXM];
  const int t = threadIdx.x;
  if (t == 0) s_m = 0;
  if (t < K1B) scnt[t] = counts[t];
  __syncthreads();
  if (t == 0) {
    int acc = 0;
    for (int b = 0; b < K1B; ++b) { soff[b] = acc; acc += scnt[b]; }
    soff[K1B] = acc;
  }
  __syncthreads();
  const int V = min(soff[K1B], MAXV);

  // stage: record d lives in segment b with soff[b] <= d < soff[b+1]
  for (int d = t; d < V; d += NTH) {
    int lo = 0, hi = K1B;                     // binary search over soff
    while (hi - lo > 1) { int mid = (lo + hi) >> 1; if (soff[mid] <= d) lo = mid; else hi = mid; }
    int i = d - soff[lo];
    const float4* src = (const float4*)(recs + ((size_t)lo * CAP + i) * 8);
    float4 r0 = src[0], r1 = src[1];
    ((float4*)srec[d])[0] = r0;
    ((float4*)srec[d])[1] = r1;
    cscore[d] = r0.x;
    cidx[d]   = __float_as_uint(r1.z);
  }
  const int V4 = (V + 3) & ~3;
  for (int e = V + t; e < V4; e += NTH) cscore[e] = -1.f;  // pad: never >, never ==
  __syncthreads();

  // rank sweep: thread t handles entries e0=2t, e1=2t+1; one b128 read
  // feeds both entries' compares (halves LDS pipe pressure vs 1/thread)
  const float4* c4 = (const float4*)cscore;
  const int nq = V4 >> 2;
  const int e0 = 2 * t, e1 = 2 * t + 1;
  const bool a0 = (e0 < V), a1 = (e1 < V);
  float s0 = a0 ? cscore[e0] : 0.f;
  float s1 = a1 ? cscore[e1] : 0.f;
  int gt0 = 0, eq0 = 0, gt1 = 0, eq1 = 0;
  if (a0) {
    for (int q = 0; q < nq; ++q) {
      float4 v = c4[q];
      gt0 += (v.x > s0) + (v.y > s0) + (v.z > s0) + (v.w > s0);
      eq0 += (v.x == s0) + (v.y == s0) + (v.z == s0) + (v.w == s0);
      gt1 += (v.x > s1) + (v.y > s1) + (v.z > s1) + (v.w > s1);
      eq1 += (v.x == s1) + (v.y == s1) + (v.z == s1) + (v.w == s1);
    }
  }
  int rank0 = gt0, rank1 = gt1;
  if (a0 && eq0 - 1 > 0) {                   // true fp tie: rare; exact fixup
    unsigned idx = cidx[e0];
    int lt = 0;
    for (int m = 0; m < V; ++m) lt += (cscore[m] == s0) && (cidx[m] < idx);
    rank0 = gt0 + lt;
  }
  if (a1 && eq1 - 1 > 0) {
    unsigned idx = cidx[e1];
    int lt = 0;
    for (int m = 0; m < V; ++m) lt += (cscore[m] == s1) && (cidx[m] < idx);
    rank1 = gt1 + lt;
  }

  // write rows; collect positive-area boxes
  #pragma unroll
  for (int h = 0; h < 2; ++h) {
    const bool act = h ? a1 : a0;
    if (!act) continue;
    const int e = h ? e1 : e0;
    const int r = h ? rank1 : rank0;
    float* row = out + (size_t)r * 5;
    row[0] = srec[e][0]; row[1] = srec[e][1]; row[2] = srec[e][2];
    row[3] = srec[e][3]; row[4] = srec[e][4];
    float area = srec[e][5];
    if (area > 0.f) {
      int p = atomicAdd(&s_m, 1);
      if (p < MAXM) {
        prank[p] = r;
        pbox[p][0] = srec[e][1]; pbox[p][1] = srec[e][2];
        pbox[p][2] = srec[e][3]; pbox[p][3] = srec[e][4];
        parea[p] = area;
      }
    }
  }
  __syncthreads();

  // sort positive-area boxes by rank (ranks distinct)
  const int M = min(s_m, MAXM);
  for (int e = t; e < M; e += NTH) {
    int r = prank[e];
    int pos = 0;
    for (int m = 0; m < M; ++m) pos += (prank[m] < r);
    srnk[pos] = r;
    sbox[pos][0] = pbox[e][0]; sbox[pos][1] = pbox[e][1];
    sbox[pos][2] = pbox[e][2]; sbox[pos][3] = pbox[e][3];
    sarea[pos] = parea[e];
    skeep[pos] = 1;
  }
  __syncthreads();

  // greedy NMS (M ~ 1, loop almost never iterates)
  for (int i = 1; i < M; ++i) {
    if (t == 0) sflag = 0;
    __syncthreads();
    if (t < i && skeep[t]) {
      float ltx = fmaxf(sbox[t][0], sbox[i][0]);
      float lty = fmaxf(sbox[t][1], sbox[i][1]);
      float rbx = fminf(sbox[t][2], sbox[i][2]);
      float rby = fminf(sbox[t][3], sbox[i][3]);
      float w = fmaxf(rbx - ltx, 0.f);
      float h = fmaxf(rby - lty, 0.f);
      float inter = w * h;
      float uni = sarea[t] + sarea[i] - inter;
      if (inter / fmaxf(uni, 1e-9f) > 0.5f) sflag = 1;
    }
    __syncthreads();
    if (t == 0 && sflag) skeep[i] = 0;
    __syncthreads();
  }

  // zero suppressed rows
  for (int e = t; e < M; e += NTH) {
    if (!skeep[e]) {
      float* row = out + (size_t)srnk[e] * 5;
      row[0] = 0.f; row[1] = 0.f; row[2] = 0.f; row[3] = 0.f; row[4] = 0.f;
    }
  }
}

// ---- Fallback: verified round-1 single-block kernel (ws too small) ----
#define FB_NTH 1024
__global__ __launch_bounds__(FB_NTH, 1) void nms_all(
    const float* __restrict__ X, float* __restrict__ out, int n, int out_n) {
  __shared__ __align__(16) float cscore[MAXV];
  __shared__ unsigned int cidx[MAXV];
  __shared__ int s_vcount, s_mcount, sflag;
  __shared__ int   prank[MAXM];
  __shared__ float pbox[MAXM][4];
  __shared__ float parea[MAXM];
  __shared__ int   srnk[MAXM];
  __shared__ float sbox[MAXM][4];
  __shared__ float sarea[MAXM];
  __shared__ int   skeep[MAXM];
  const int t = threadIdx.x;
  if (t == 0) { s_vcount = 0; s_mcount = 0; }
  const float4* X4 = (const float4*)X;
  const int n4 = n >> 2;
  float4 sc0 = make_float4(-1.f, -1.f, -1.f, -1.f);
  float4 sc1 = sc0;
  if (t < n4)           sc0 = X4[t];
  if (t + FB_NTH < n4)  sc1 = X4[t + FB_NTH];
  float4* out4 = (float4*)out;
  const int o4 = out_n >> 2;
  for (int i = t; i < o4; i += FB_NTH) out4[i] = make_float4(0.f, 0.f, 0.f, 0.f);
  for (int i = (o4 << 2) + t; i < out_n; i += FB_NTH) out[i] = 0.f;
  __syncthreads();
  if (t < n4) {
    float v[4] = {sc0.x, sc0.y, sc0.z, sc0.w};
    #pragma unroll
    for (int k = 0; k < 4; ++k)
      if (v[k] > 0.9f) {
        int p = atomicAdd(&s_vcount, 1);
        if (p < MAXV) { cscore[p] = v[k]; cidx[p] = (unsigned)(4 * t + k); }
      }
  }
  if (t + FB_NTH < n4) {
    float v[4] = {sc1.x, sc1.y, sc1.z, sc1.w};
    #pragma unroll
    for (int k = 0; k < 4; ++k)
      if (v[k] > 0.9f) {
        int p = atomicAdd(&s_vcount, 1);
        if (p < MAXV) { cscore[p] = v[k]; cidx[p] = (unsigned)(4 * (t + FB_NTH) + k); }
      }
  }
  for (int i = (n4 << 2) + t; i < n; i += FB_NTH) {
    float s = X[i];
    if (s > 0.9f) {
      int p = atomicAdd(&s_vcount, 1);
      if (p < MAXV) { cscore[p] = s; cidx[p] = (unsigned)i; }
    }
  }
  __syncthreads();
  const int V = min(s_vcount, MAXV);
  const int V4 = (V + 3) & ~3;
  for (int e = V + t; e < V4; e += FB_NTH) cscore[e] = -1.f;
  __syncthreads();
  const float4* c4 = (const float4*)cscore;
  const int nq = V4 >> 2;
  for (int e = t; e < V; e += FB_NTH) {
    float s = cscore[e];
    unsigned idx = cidx[e];
    int gt = 0, eq = 0;
    for (int q = 0; q < nq; ++q) {
      float4 v = c4[q];
      gt += (v.x > s) + (v.y > s) + (v.z > s) + (v.w > s);
      eq += (v.x == s) + (v.y == s) + (v.z == s) + (v.w == s);
    }
    eq -= 1;
    int rank = gt;
    if (eq > 0) {
      int lt = 0;
      for (int m = 0; m < V; ++m) lt += (cscore[m] == s) && (cidx[m] < idx);
      rank += lt;
    }
    float f1 = X[n + idx], f2 = X[2 * n + idx];
    float f3 = X[3 * n + idx], f4v = X[4 * n + idx];
    float c2 = s + f2, c3 = f1 + f3;
    float* row = out + (size_t)rank * 5;
    row[0] = s; row[1] = f1; row[2] = c2; row[3] = c3; row[4] = f4v;
    float w = fmaxf(c3 - f1, 0.f);
    float h = fmaxf(f4v - c2, 0.f);
    float area = w * h;
    if (area > 0.f) {
      int p = atomicAdd(&s_mcount, 1);
      if (p < MAXM) {
        prank[p] = rank;
        pbox[p][0] = f1; pbox[p][1] = c2; pbox[p][2] = c3; pbox[p][3] = f4v;
        parea[p] = area;
      }
    }
  }
  __syncthreads();
  const int M = min(s_mcount, MAXM);
  for (int e = t; e < M; e += FB_NTH) {
    int r = prank[e];
    int pos = 0;
    for (int m = 0; m < M; ++m) pos += (prank[m] < r);
    srnk[pos] = r;
    sbox[pos][0] = pbox[e][0]; sbox[pos][1] = pbox[e][1];
    sbox[pos][2] = pbox[e][2]; sbox[pos][3] = pbox[e][3];
    sarea[pos] = parea[e];
    skeep[pos] = 1;
  }
  __syncthreads();
  for (int i = 1; i < M; ++i) {
    if (t == 0) sflag = 0;
    __syncthreads();
    if (t < i && skeep[t]) {
      float ltx = fmaxf(sbox[t][0], sbox[i][0]);
      float lty = fmaxf(sbox[t][1], sbox[i][1]);
      float rbx = fminf(sbox[t][2], sbox[i][2]);
      float rby = fminf(sbox[t][3], sbox[i][3]);
      float w = fmaxf(rbx - ltx, 0.f);
      float h = fmaxf(rby - lty, 0.f);
      float inter = w * h;
      float uni = sarea[t] + sarea[i] - inter;
      if (inter / fmaxf(uni, 1e-9f) > 0.5f) sflag = 1;
    }
    __syncthreads();
    if (t == 0 && sflag) skeep[i] = 0;
    __syncthreads();
  }
  for (int e = t; e < M; e += FB_NTH) {
    if (!skeep[e]) {
      float* row = out + (size_t)srnk[e] * 5;
      row[0] = 0.f; row[1] = 0.f; row[2] = 0.f; row[3] = 0.f; row[4] = 0.f;
    }
  }
}

extern "C" void kernel_launch(void* const* d_in, const int* in_sizes, int n_in,
                              void* d_out, int out_size, void* d_ws, size_t ws_size,
                              hipStream_t stream) {
  const float* X = (const float*)d_in[0];
  float* out = (float*)d_out;
  int n = in_sizes[0] / 5;   // 6400
  size_t need = 256 + (size_t)K1B * CAP * 8 * sizeof(float);
  if (ws_size >= need) {
    int* counts = (int*)d_ws;
    float* recs = (float*)((char*)d_ws + 256);
    hipLaunchKernelGGL(k_compact, dim3(K1B), dim3(K1T), 0, stream,
                       X, out, recs, counts, n, out_size);
    hipLaunchKernelGGL(k_rank_nms, dim3(1), dim3(NTH), 0, stream,
                       recs, counts, out);
  } else {
    hipLaunchKernelGGL(nms_all, dim3(1), dim3(FB_NTH), 0, stream, X, out, n, out_size);
  }
}